// Round 5
// baseline (23.700 us; speedup 1.0000x reference)
//
#include <hip/hip_runtime.h>

constexpr int Q    = 20;
constexpr int EMB  = 64;
constexpr int Bsz  = 16, H = 48, W = 48;
constexpr int HW   = H * W;          // 2304
constexpr int NPIX = Bsz * HW;       // 36864
constexpr int BLOCK = 128;
constexpr int TPP   = 4;             // threads per pixel
constexpr int PIXPB = BLOCK / TPP;   // 32 pixels per block
constexpr int NBLK  = NPIX / PIXPB;  // 1152 blocks

// LDS combined table: 14 coefficient rows + 1 base row.
// rows 0-4  : w2[0]*(T[k]-T[5])        k=0..4   (coef cT[k])
// rows 5-8  : w2[1]*(D[k]-D[4])        k=0..3   (coef cD[k])
// rows 9-12 : w2[2]*(R[k]-R[4])        k=0..3   (coef cR[k])
// row  13   : w2[4]*(P[1]-P[0])                 (coef rep)
// row  14   : sumw1*(w2[0]T5 + w2[1]D4 + w2[2]R4 + w2[4]P0)   (coef 1)
__global__ __launch_bounds__(BLOCK)
void act_pre_kernel(const int* __restrict__ unit,
                    const int* __restrict__ atp,  const int* __restrict__ dirp,
                    const int* __restrict__ resp, const int* __restrict__ repp,
                    const float* __restrict__ amtp, const float* __restrict__ np_,
                    const float* __restrict__ Ttab, const float* __restrict__ Dtab,
                    const float* __restrict__ Rtab, const float* __restrict__ Ptab,
                    const float* __restrict__ w1p,  const float* __restrict__ b1p,
                    const float* __restrict__ w2p,  const float* __restrict__ b2p,
                    float* __restrict__ out)
{
    __shared__ float sc[15][EMB];

    const int tid = threadIdx.x;
    const int pIB = tid >> 2;          // pixel within block (0..31)
    const int t   = tid & 3;           // sub-thread within pixel
    const int pix = blockIdx.x * PIXPB + pIB;

    // ---- issue ALL per-pixel global loads first (overlap table-fill latency) ----
    const int base = pix * Q + t * 4;
    const int4   av = *reinterpret_cast<const int4*>(atp  + base);
    const int4   dv = *reinterpret_cast<const int4*>(dirp + base);
    const int4   rv = *reinterpret_cast<const int4*>(resp + base);
    const int4   pv = *reinterpret_cast<const int4*>(repp + base);
    const float4 mv = *reinterpret_cast<const float4*>(amtp + base);
    const float4 nv = *reinterpret_cast<const float4*>(np_  + base);
    const int tail  = pix * Q + 16 + t;
    const int   as = atp[tail],  ds2 = dirp[tail], rs = resp[tail], ps = repp[tail];
    const float ms = amtp[tail], ns = np_[tail];
    const int   uu = unit[pix];
    const float4 wv = *reinterpret_cast<const float4*>(w1p + t * 4);  // w1[4t..4t+4)
    const float  ws = w1p[16 + t];                                    // w1[16+t]

    // uniform scalars (s_load, L2-hot)
    const float w20 = w2p[0], w21 = w2p[1], w22 = w2p[2];
    const float w23 = w2p[3], w24 = w2p[4], w25 = w2p[5];
    const float constC = b1p[0] * (w20 + w21 + w22 + w23 + w24 + w25) + b2p[0];

    // ---- LDS table fill (its global loads overlap the pixel loads above) ----
    for (int i = tid; i < 15 * EMB; i += BLOCK) {
        const int row = i >> 6, e = i & 63;
        float v;
        if (row < 5)        v = w20 * (Ttab[row * EMB + e]       - Ttab[5 * EMB + e]);
        else if (row < 9)   v = w21 * (Dtab[(row - 5) * EMB + e] - Dtab[4 * EMB + e]);
        else if (row < 13)  v = w22 * (Rtab[(row - 9) * EMB + e] - Rtab[4 * EMB + e]);
        else if (row == 13) v = w24 * (Ptab[EMB + e] - Ptab[e]);
        else {
            float sumw = 0.f;
            #pragma unroll
            for (int q = 0; q < Q; ++q) sumw += w1p[q];
            v = sumw * (w20 * Ttab[5 * EMB + e] + w21 * Dtab[4 * EMB + e]
                      + w22 * Rtab[4 * EMB + e] + w24 * Ptab[e]);
        }
        sc[row][e] = v;
    }

    // ---- coefficient accumulation (register-only; runs before the barrier) ----
    const int   ai[5] = {av.x, av.y, av.z, av.w, as};
    const int   di[5] = {dv.x, dv.y, dv.z, dv.w, ds2};
    const int   ri[5] = {rv.x, rv.y, rv.z, rv.w, rs};
    const int   pi[5] = {pv.x, pv.y, pv.z, pv.w, ps};
    const float mf[5] = {mv.x, mv.y, mv.z, mv.w, ms};
    const float nf[5] = {nv.x, nv.y, nv.z, nv.w, ns};
    const float wf[5] = {wv.x, wv.y, wv.z, wv.w, ws};

    float cT[5] = {}, cD[4] = {}, cR[4] = {};
    float rep = 0.f, amtAcc = 0.f, nAcc = 0.f;
    #pragma unroll
    for (int j = 0; j < 5; ++j) {
        const float wq = wf[j];
        #pragma unroll
        for (int k = 0; k < 5; ++k) cT[k] += (ai[j] == k) ? wq : 0.f;
        #pragma unroll
        for (int k = 0; k < 4; ++k) cD[k] += (di[j] == k) ? wq : 0.f;
        #pragma unroll
        for (int k = 0; k < 4; ++k) cR[k] += (ri[j] == k) ? wq : 0.f;
        rep    += (pi[j] != 0) ? wq : 0.f;
        amtAcc += wq * mf[j];
        nAcc   += wq * nf[j];
    }

    // ---- butterfly allreduce across the 4 threads of this pixel ----
    #define RED4(x) { x += __shfl_xor(x, 1); x += __shfl_xor(x, 2); }
    #pragma unroll
    for (int k = 0; k < 5; ++k) RED4(cT[k]);
    #pragma unroll
    for (int k = 0; k < 4; ++k) RED4(cD[k]);
    #pragma unroll
    for (int k = 0; k < 4; ++k) RED4(cR[k]);
    RED4(rep); RED4(amtAcc); RED4(nAcc);
    #undef RED4

    const float scalar = w23 * amtAcc + w25 * nAcc + constC;
    const float ind = (uu != 0) ? 1.f : 0.f;

    float coef[14];
    #pragma unroll
    for (int k = 0; k < 5; ++k) coef[k] = cT[k];
    #pragma unroll
    for (int k = 0; k < 4; ++k) coef[5 + k] = cD[k];
    #pragma unroll
    for (int k = 0; k < 4; ++k) coef[9 + k] = cR[k];
    coef[13] = rep;

    const int b  = pix / HW;
    const int hw = pix - b * HW;
    float* outp = out + b * (EMB * HW) + hw;

    __syncthreads();   // table ready; coefficient work already done

    // ---- each thread computes 16 channels: e in [16t, 16t+16) ----
    #pragma unroll
    for (int i = 0; i < 4; ++i) {
        const int e0 = t * 16 + i * 4;
        const float4 bv = *reinterpret_cast<const float4*>(&sc[14][e0]);
        float va0 = scalar + bv.x, va1 = scalar + bv.y;
        float va2 = scalar + bv.z, va3 = scalar + bv.w;
        #pragma unroll
        for (int k = 0; k < 14; ++k) {
            const float4 sv = *reinterpret_cast<const float4*>(&sc[k][e0]);
            va0 += coef[k] * sv.x;
            va1 += coef[k] * sv.y;
            va2 += coef[k] * sv.z;
            va3 += coef[k] * sv.w;
        }
        va0 = ((va0 >= 0.f) ? va0 : 0.01f * va0) * ind;
        va1 = ((va1 >= 0.f) ? va1 : 0.01f * va1) * ind;
        va2 = ((va2 >= 0.f) ? va2 : 0.01f * va2) * ind;
        va3 = ((va3 >= 0.f) ? va3 : 0.01f * va3) * ind;
        outp[(e0 + 0) * HW] = va0;
        outp[(e0 + 1) * HW] = va1;
        outp[(e0 + 2) * HW] = va2;
        outp[(e0 + 3) * HW] = va3;
    }
}

extern "C" void kernel_launch(void* const* d_in, const int* in_sizes, int n_in,
                              void* d_out, int out_size, void* d_ws, size_t ws_size,
                              hipStream_t stream) {
    const int*   unit = (const int*)  d_in[0];
    const int*   atp  = (const int*)  d_in[1];
    const int*   dirp = (const int*)  d_in[2];
    const int*   resp = (const int*)  d_in[3];
    const int*   repp = (const int*)  d_in[4];
    const float* amtp = (const float*)d_in[5];
    const float* np_  = (const float*)d_in[6];
    const float* Ttab = (const float*)d_in[7];
    const float* Dtab = (const float*)d_in[8];
    const float* Rtab = (const float*)d_in[9];
    const float* Ptab = (const float*)d_in[10];
    const float* w1p  = (const float*)d_in[11];
    const float* b1p  = (const float*)d_in[12];
    const float* w2p  = (const float*)d_in[13];
    const float* b2p  = (const float*)d_in[14];
    float* out = (float*)d_out;

    // PROBE ROUND: launch the identical kernel TWICE (idempotent — writes the
    // same output both times). Measures marginal per-kernel cost T via
    // dur = ov + 2T + gap, discriminating "fixed replay floor" (~18-20 us)
    // from "kernel really is 14 us" (~27-29 us).
    act_pre_kernel<<<NBLK, BLOCK, 0, stream>>>(
        unit, atp, dirp, resp, repp, amtp, np_,
        Ttab, Dtab, Rtab, Ptab, w1p, b1p, w2p, b2p, out);
    act_pre_kernel<<<NBLK, BLOCK, 0, stream>>>(
        unit, atp, dirp, resp, repp, amtp, np_,
        Ttab, Dtab, Rtab, Ptab, w1p, b1p, w2p, b2p, out);
}

// Round 6
// 19.015 us; speedup vs baseline: 1.2464x; 1.2464x over previous
//
#include <hip/hip_runtime.h>

constexpr int Q    = 20;
constexpr int EMB  = 64;
constexpr int Bsz  = 16, H = 48, W = 48;
constexpr int HW   = H * W;          // 2304
constexpr int NPIX = Bsz * HW;       // 36864
constexpr int BLOCK = 128;
constexpr int TPP   = 4;             // threads per pixel
constexpr int PXPT  = 2;             // pixels per thread
constexpr int PIXPB = BLOCK / TPP * PXPT;  // 64 pixels per block
constexpr int NBLK  = NPIX / PIXPB;        // 576 blocks

// LDS table: rows 0-4: w2[0]*(T[k]-T[5]); 5-8: w2[1]*(D[k]-D[4]);
// 9-12: w2[2]*(R[k]-R[4]); 13: w2[4]*(P[1]-P[0]);
// 14: sumw1*(w2[0]T5 + w2[1]D4 + w2[2]R4 + w2[4]P0)
__global__ __launch_bounds__(BLOCK)
void act_pre_kernel(const int* __restrict__ unit,
                    const int* __restrict__ atp,  const int* __restrict__ dirp,
                    const int* __restrict__ resp, const int* __restrict__ repp,
                    const float* __restrict__ amtp, const float* __restrict__ np_,
                    const float* __restrict__ Ttab, const float* __restrict__ Dtab,
                    const float* __restrict__ Rtab, const float* __restrict__ Ptab,
                    const float* __restrict__ w1p,  const float* __restrict__ b1p,
                    const float* __restrict__ w2p,  const float* __restrict__ b2p,
                    float* __restrict__ out)
{
    __shared__ float sc[15][EMB];

    const int tid  = threadIdx.x;
    const int pIB  = tid >> 2;               // 0..31
    const int t    = tid & 3;                // 0..3
    const int pixA = blockIdx.x * PIXPB + pIB;
    const int pixB = pixA + 32;

    // ---- issue ALL per-pixel global loads for BOTH pixels up-front ----
    const int baseA = pixA * Q + t * 4, tailA = pixA * Q + 16 + t;
    const int baseB = pixB * Q + t * 4, tailB = pixB * Q + 16 + t;
    const int4   avA = *reinterpret_cast<const int4*>(atp  + baseA);
    const int4   dvA = *reinterpret_cast<const int4*>(dirp + baseA);
    const int4   rvA = *reinterpret_cast<const int4*>(resp + baseA);
    const int4   pvA = *reinterpret_cast<const int4*>(repp + baseA);
    const float4 mvA = *reinterpret_cast<const float4*>(amtp + baseA);
    const float4 nvA = *reinterpret_cast<const float4*>(np_  + baseA);
    const int4   avB = *reinterpret_cast<const int4*>(atp  + baseB);
    const int4   dvB = *reinterpret_cast<const int4*>(dirp + baseB);
    const int4   rvB = *reinterpret_cast<const int4*>(resp + baseB);
    const int4   pvB = *reinterpret_cast<const int4*>(repp + baseB);
    const float4 mvB = *reinterpret_cast<const float4*>(amtp + baseB);
    const float4 nvB = *reinterpret_cast<const float4*>(np_  + baseB);
    const int   asA = atp[tailA], dsA = dirp[tailA], rsA = resp[tailA], psA = repp[tailA];
    const float msA = amtp[tailA], nsA = np_[tailA];
    const int   asB = atp[tailB], dsB = dirp[tailB], rsB = resp[tailB], psB = repp[tailB];
    const float msB = amtp[tailB], nsB = np_[tailB];
    const int   uuA = unit[pixA], uuB = unit[pixB];
    const float4 wv = *reinterpret_cast<const float4*>(w1p + t * 4);
    const float  ws = w1p[16 + t];

    // row-14 ingredient loads (tid<64), hoisted early
    float tv5 = 0.f, dv4 = 0.f, rv4 = 0.f, pv0 = 0.f;
    if (tid < EMB) {
        tv5 = Ttab[5 * EMB + tid];
        dv4 = Dtab[4 * EMB + tid];
        rv4 = Rtab[4 * EMB + tid];
        pv0 = Ptab[tid];
    }

    // uniform scalars
    const float w20 = w2p[0], w21 = w2p[1], w22 = w2p[2];
    const float w23 = w2p[3], w24 = w2p[4], w25 = w2p[5];
    const float constC = b1p[0] * (w20 + w21 + w22 + w23 + w24 + w25) + b2p[0];

    // ---- LDS fill rows 0-13 (896 elems = exactly 7 iterations) ----
    #pragma unroll
    for (int it = 0; it < 7; ++it) {
        const int i = it * BLOCK + tid;
        const int row = i >> 6, e = i & 63;
        float v;
        if (row < 5)       v = w20 * (Ttab[row * EMB + e]       - Ttab[5 * EMB + e]);
        else if (row < 9)  v = w21 * (Dtab[(row - 5) * EMB + e] - Dtab[4 * EMB + e]);
        else if (row < 13) v = w22 * (Rtab[(row - 9) * EMB + e] - Rtab[4 * EMB + e]);
        else               v = w24 * (Ptab[EMB + e] - Ptab[e]);
        sc[row][e] = v;
    }

    // ---- coefficient accumulation, both pixels (register-only) ----
    const float wf[5] = {wv.x, wv.y, wv.z, wv.w, ws};
    float sumwT = wv.x + wv.y + wv.z + wv.w + ws;

    float cTA[5] = {}, cDA[4] = {}, cRA[4] = {}, repA = 0.f, amtA = 0.f, nA = 0.f;
    float cTB[5] = {}, cDB[4] = {}, cRB[4] = {}, repB = 0.f, amtB = 0.f, nB = 0.f;
    {
        const int   aiA[5] = {avA.x, avA.y, avA.z, avA.w, asA};
        const int   diA[5] = {dvA.x, dvA.y, dvA.z, dvA.w, dsA};
        const int   riA[5] = {rvA.x, rvA.y, rvA.z, rvA.w, rsA};
        const int   piA[5] = {pvA.x, pvA.y, pvA.z, pvA.w, psA};
        const float mfA[5] = {mvA.x, mvA.y, mvA.z, mvA.w, msA};
        const float nfA[5] = {nvA.x, nvA.y, nvA.z, nvA.w, nsA};
        const int   aiB[5] = {avB.x, avB.y, avB.z, avB.w, asB};
        const int   diB[5] = {dvB.x, dvB.y, dvB.z, dvB.w, dsB};
        const int   riB[5] = {rvB.x, rvB.y, rvB.z, rvB.w, rsB};
        const int   piB[5] = {pvB.x, pvB.y, pvB.z, pvB.w, psB};
        const float mfB[5] = {mvB.x, mvB.y, mvB.z, mvB.w, msB};
        const float nfB[5] = {nvB.x, nvB.y, nvB.z, nvB.w, nsB};
        #pragma unroll
        for (int j = 0; j < 5; ++j) {
            const float wq = wf[j];
            #pragma unroll
            for (int k = 0; k < 5; ++k) {
                cTA[k] += (aiA[j] == k) ? wq : 0.f;
                cTB[k] += (aiB[j] == k) ? wq : 0.f;
            }
            #pragma unroll
            for (int k = 0; k < 4; ++k) {
                cDA[k] += (diA[j] == k) ? wq : 0.f;
                cDB[k] += (diB[j] == k) ? wq : 0.f;
            }
            #pragma unroll
            for (int k = 0; k < 4; ++k) {
                cRA[k] += (riA[j] == k) ? wq : 0.f;
                cRB[k] += (riB[j] == k) ? wq : 0.f;
            }
            repA += (piA[j] != 0) ? wq : 0.f;
            repB += (piB[j] != 0) ? wq : 0.f;
            amtA += wq * mfA[j];  amtB += wq * mfB[j];
            nA   += wq * nfA[j];  nB   += wq * nfB[j];
        }
    }

    // ---- butterfly allreduce over the 4 threads of each pixel ----
    #define RED4(x) { x += __shfl_xor(x, 1); x += __shfl_xor(x, 2); }
    #pragma unroll
    for (int k = 0; k < 5; ++k) { RED4(cTA[k]); RED4(cTB[k]); }
    #pragma unroll
    for (int k = 0; k < 4; ++k) { RED4(cDA[k]); RED4(cDB[k]); }
    #pragma unroll
    for (int k = 0; k < 4; ++k) { RED4(cRA[k]); RED4(cRB[k]); }
    RED4(repA); RED4(repB); RED4(amtA); RED4(amtB); RED4(nA); RED4(nB);
    RED4(sumwT);
    #undef RED4

    // ---- row 14 (needs sumw) then the single barrier ----
    if (tid < EMB)
        sc[14][tid] = sumwT * (w20 * tv5 + w21 * dv4 + w22 * rv4 + w24 * pv0);

    const float scalarA = w23 * amtA + w25 * nA + constC;
    const float scalarB = w23 * amtB + w25 * nB + constC;
    const float indA = (uuA != 0) ? 1.f : 0.f;
    const float indB = (uuB != 0) ? 1.f : 0.f;

    float cfA[14], cfB[14];
    #pragma unroll
    for (int k = 0; k < 5; ++k) { cfA[k] = cTA[k]; cfB[k] = cTB[k]; }
    #pragma unroll
    for (int k = 0; k < 4; ++k) { cfA[5 + k] = cDA[k]; cfB[5 + k] = cDB[k]; }
    #pragma unroll
    for (int k = 0; k < 4; ++k) { cfA[9 + k] = cRA[k]; cfB[9 + k] = cRB[k]; }
    cfA[13] = repA; cfB[13] = repB;

    const int b  = pixA / HW;                 // pixB is same batch image (+32 within row-block)
    const int hw = pixA - b * HW;
    float* outpA = out + b * (EMB * HW) + hw;
    float* outpB = outpA + 32;

    __syncthreads();

    // ---- shared epilogue: ONE table read feeds BOTH pixels ----
    #pragma unroll
    for (int i = 0; i < 4; ++i) {
        const int e0 = t * 16 + i * 4;
        const float4 bv = *reinterpret_cast<const float4*>(&sc[14][e0]);
        float a0 = scalarA + bv.x, a1 = scalarA + bv.y, a2 = scalarA + bv.z, a3 = scalarA + bv.w;
        float b0 = scalarB + bv.x, b1 = scalarB + bv.y, b2 = scalarB + bv.z, b3 = scalarB + bv.w;
        #pragma unroll
        for (int k = 0; k < 14; ++k) {
            const float4 sv = *reinterpret_cast<const float4*>(&sc[k][e0]);
            a0 += cfA[k] * sv.x;  b0 += cfB[k] * sv.x;
            a1 += cfA[k] * sv.y;  b1 += cfB[k] * sv.y;
            a2 += cfA[k] * sv.z;  b2 += cfB[k] * sv.z;
            a3 += cfA[k] * sv.w;  b3 += cfB[k] * sv.w;
        }
        a0 = ((a0 >= 0.f) ? a0 : 0.01f * a0) * indA;
        a1 = ((a1 >= 0.f) ? a1 : 0.01f * a1) * indA;
        a2 = ((a2 >= 0.f) ? a2 : 0.01f * a2) * indA;
        a3 = ((a3 >= 0.f) ? a3 : 0.01f * a3) * indA;
        b0 = ((b0 >= 0.f) ? b0 : 0.01f * b0) * indB;
        b1 = ((b1 >= 0.f) ? b1 : 0.01f * b1) * indB;
        b2 = ((b2 >= 0.f) ? b2 : 0.01f * b2) * indB;
        b3 = ((b3 >= 0.f) ? b3 : 0.01f * b3) * indB;
        outpA[(e0 + 0) * HW] = a0;  outpB[(e0 + 0) * HW] = b0;
        outpA[(e0 + 1) * HW] = a1;  outpB[(e0 + 1) * HW] = b1;
        outpA[(e0 + 2) * HW] = a2;  outpB[(e0 + 2) * HW] = b2;
        outpA[(e0 + 3) * HW] = a3;  outpB[(e0 + 3) * HW] = b3;
    }
}

extern "C" void kernel_launch(void* const* d_in, const int* in_sizes, int n_in,
                              void* d_out, int out_size, void* d_ws, size_t ws_size,
                              hipStream_t stream) {
    const int*   unit = (const int*)  d_in[0];
    const int*   atp  = (const int*)  d_in[1];
    const int*   dirp = (const int*)  d_in[2];
    const int*   resp = (const int*)  d_in[3];
    const int*   repp = (const int*)  d_in[4];
    const float* amtp = (const float*)d_in[5];
    const float* np_  = (const float*)d_in[6];
    const float* Ttab = (const float*)d_in[7];
    const float* Dtab = (const float*)d_in[8];
    const float* Rtab = (const float*)d_in[9];
    const float* Ptab = (const float*)d_in[10];
    const float* w1p  = (const float*)d_in[11];
    const float* b1p  = (const float*)d_in[12];
    const float* w2p  = (const float*)d_in[13];
    const float* b2p  = (const float*)d_in[14];
    float* out = (float*)d_out;

    act_pre_kernel<<<NBLK, BLOCK, 0, stream>>>(
        unit, atp, dirp, resp, repp, amtp, np_,
        Ttab, Dtab, Rtab, Ptab, w1p, b1p, w2p, b2p, out);
}